// Round 4
// baseline (259499.976 us; speedup 1.0000x reference)
//
#include <hip/hip_runtime.h>
#include <cstddef>

#define NSTEP 4096

// All device pointers the step kernel needs, passed by value.
struct Params {
  const float* xn;        // (4096, 64) normalized input
  const float* w_ih[4];
  const float* w_hh[4];
  const float* b_ih[4];
  const float* b_hh[4];
  float* h[4];            // double buffers: h[l] holds 2*H_l floats, parity t&1
  float* c[4];            // single buffer per layer
  float* out;             // (4096, 256) flat
  int s;                  // launch index
};

// BatchNorm1d over timestep channels: per t, stats over (B=4, F=64) = 256 vals.
__global__ __launch_bounds__(256) void bn_kernel(const float* __restrict__ x,
                                                 const float* __restrict__ bn_w,
                                                 const float* __restrict__ bn_b,
                                                 float* __restrict__ xn)
{
  const int t   = blockIdx.x;        // 0..1023
  const int tid = threadIdx.x;       // 256 = B*F
  const int b   = tid >> 6;
  const int f   = tid & 63;
  const float v = x[((size_t)b * 1024 + t) * 64 + f];
  float s = v, ss = v * v;
  #pragma unroll
  for (int off = 32; off > 0; off >>= 1) {
    s  += __shfl_down(s, off);
    ss += __shfl_down(ss, off);
  }
  __shared__ float sh[8];
  const int w = tid >> 6;
  if ((tid & 63) == 0) { sh[w] = s; sh[4 + w] = ss; }
  __syncthreads();
  const float S    = sh[0] + sh[1] + sh[2] + sh[3];
  const float SS   = sh[4] + sh[5] + sh[6] + sh[7];
  const float mean = S * (1.0f / 256.0f);
  const float var  = SS * (1.0f / 256.0f) - mean * mean;  // biased, matches jnp.var
  const float inv  = rsqrtf(var + 1e-5f);
  const float scale = bn_w[t] * inv;
  const float shift = bn_b[t] - mean * scale;
  // scan order: step index = b*1024 + t
  xn[((size_t)b * 1024 + t) * 64 + f] = v * scale + shift;
}

// One launch = one pipeline slot: L1 does step s, L2 step s-1, L3 s-2, L4 s-3.
// One wave per h-index; the wave computes all 4 gate rows (i,f,g,o) for that
// h, reduces, and lane 0 applies activations + state update. No LDS needed.
__global__ __launch_bounds__(256) void step_kernel(Params p)
{
  const int lane = threadIdx.x & 63;
  const int W = blockIdx.x * 4 + (threadIdx.x >> 6);  // global wave id, 0..3839

  int layer, h, H, IN, t;
  if (W < 2048)      { layer = 0; h = W;        H = 2048; IN = 64;   t = p.s;     }
  else if (W < 3072) { layer = 1; h = W - 2048; H = 1024; IN = 2048; t = p.s - 1; }
  else if (W < 3584) { layer = 2; h = W - 3072; H = 512;  IN = 1024; t = p.s - 2; }
  else               { layer = 3; h = W - 3584; H = 256;  IN = 512;  t = p.s - 3; }
  if (t < 0 || t >= NSTEP) return;

  const float* xin;
  if (layer == 0) xin = p.xn + (size_t)t * 64;
  else            xin = p.h[layer - 1] + (size_t)(t & 1) * IN;  // prev layer, same step
  const float* hprev = p.h[layer] + (size_t)((t + 1) & 1) * H;  // own layer, step t-1
  float*       hout  = p.h[layer] + (size_t)(t & 1) * H;
  const float* wih = p.w_ih[layer];
  const float* whh = p.w_hh[layer];

  float acc[4];
  #pragma unroll
  for (int g = 0; g < 4; ++g) {
    const size_t r = (size_t)g * H + h;   // PyTorch gate order: i, f, g, o
    const float* wi = wih + r * IN;
    const float* wh = whh + r * (size_t)H;
    float a = 0.0f;
    for (int k = lane; k < IN; k += 64) a += wi[k] * xin[k];
    for (int k = lane; k < H;  k += 64) a += wh[k] * hprev[k];
    acc[g] = a;
  }
  #pragma unroll
  for (int off = 32; off > 0; off >>= 1) {
    #pragma unroll
    for (int g = 0; g < 4; ++g) acc[g] += __shfl_down(acc[g], off);
  }
  if (lane == 0) {
    const float* bi = p.b_ih[layer];
    const float* bh = p.b_hh[layer];
    const float gi = acc[0] + bi[h]         + bh[h];
    const float gf = acc[1] + bi[H + h]     + bh[H + h];
    const float gg = acc[2] + bi[2 * H + h] + bh[2 * H + h];
    const float go = acc[3] + bi[3 * H + h] + bh[3 * H + h];
    const float ig = 1.0f / (1.0f + expf(-gi));
    const float fg = 1.0f / (1.0f + expf(-gf));
    const float og = 1.0f / (1.0f + expf(-go));
    const float gt = tanhf(gg);
    const float cn = fg * p.c[layer][h] + ig * gt;
    const float hn = og * tanhf(cn);
    p.c[layer][h] = cn;
    hout[h] = hn;
    if (layer == 3) p.out[(size_t)t * 256 + h] = hn;
  }
}

extern "C" void kernel_launch(void* const* d_in, const int* in_sizes, int n_in,
                              void* d_out, int out_size, void* d_ws, size_t ws_size,
                              hipStream_t stream)
{
  Params p;
  const float* x    = (const float*)d_in[0];
  const float* bn_w = (const float*)d_in[1];
  const float* bn_b = (const float*)d_in[2];
  for (int l = 0; l < 4; ++l) {
    p.w_ih[l] = (const float*)d_in[3 + 4 * l];
    p.w_hh[l] = (const float*)d_in[4 + 4 * l];
    p.b_ih[l] = (const float*)d_in[5 + 4 * l];
    p.b_hh[l] = (const float*)d_in[6 + 4 * l];
  }

  float* ws = (float*)d_ws;
  float* xn = ws;                    // 4096*64 floats
  float* st = ws + (size_t)4096 * 64;
  p.xn = xn;
  const int Hs[4] = {2048, 1024, 512, 256};
  float* cur = st;
  for (int l = 0; l < 4; ++l) { p.h[l] = cur; cur += 2 * Hs[l]; }
  for (int l = 0; l < 4; ++l) { p.c[l] = cur; cur += Hs[l]; }
  p.out = (float*)d_out;

  const size_t state_bytes = (size_t)(cur - st) * sizeof(float);
  hipMemsetAsync(st, 0, state_bytes, stream);          // zero h/c each call

  bn_kernel<<<1024, 256, 0, stream>>>(x, bn_w, bn_b, xn);

  for (int s = 0; s < NSTEP + 3; ++s) {
    p.s = s;
    step_kernel<<<960, 256, 0, stream>>>(p);
  }
}

// Round 5
// 103293.103 us; speedup vs baseline: 2.5123x; 2.5123x over previous
//
#include <hip/hip_runtime.h>
#include <cstddef>

#define NSTEP 4096

// ===================== BatchNorm over timestep channels =====================
__global__ __launch_bounds__(256) void bn_kernel(const float* __restrict__ x,
                                                 const float* __restrict__ bn_w,
                                                 const float* __restrict__ bn_b,
                                                 float* __restrict__ xn)
{
  const int t   = blockIdx.x;        // 0..1023
  const int tid = threadIdx.x;       // 256 = B*F
  const int b   = tid >> 6;
  const int f   = tid & 63;
  const float v = x[((size_t)b * 1024 + t) * 64 + f];
  float s = v, ss = v * v;
  #pragma unroll
  for (int off = 32; off > 0; off >>= 1) {
    s  += __shfl_down(s, off);
    ss += __shfl_down(ss, off);
  }
  __shared__ float sh[8];
  const int w = tid >> 6;
  if ((tid & 63) == 0) { sh[w] = s; sh[4 + w] = ss; }
  __syncthreads();
  const float S    = sh[0] + sh[1] + sh[2] + sh[3];
  const float SS   = sh[4] + sh[5] + sh[6] + sh[7];
  const float mean = S * (1.0f / 256.0f);
  const float var  = SS * (1.0f / 256.0f) - mean * mean;  // biased, matches jnp.var
  const float inv  = rsqrtf(var + 1e-5f);
  const float scale = bn_w[t] * inv;
  const float shift = bn_b[t] - mean * scale;
  xn[((size_t)b * 1024 + t) * 64 + f] = v * scale + shift;
}

// ===================== Persistent weight-stationary LSTM layer ==============
// One kernel runs all 4096 steps of one layer. Each wave owns one h-unit
// (SPLIT=1) or half of one h-unit's K-range (SPLIT=2). Weights live in VGPRs
// for the whole kernel. Recurrence h(t-1) is read from the layer's own output
// trace Hout (row t == h(t-1), row 0 pre-zeroed), so no parity buffer is
// needed; one grid barrier per step orders write(t) before read(t) next step.
//
// Grid barrier: cumulative (never reset) two-level counter in d_ws.
//   - tid0 of each block: release fence -> group fetch_add; group-last bumps
//     root; all poll root; acquire fence -> L1/L2 invalidated for fresh reads.
//   - __syncthreads() before release drains every wave's stores to L2
//     (compiler emits per-wave s_waitcnt vmcnt(0) before s_barrier).
template<int H, int IN, int SPLIT, int NBLK, bool LAST>
__global__ __launch_bounds__(512, 2)
void lstm_layer(const float* __restrict__ win,   // w_ih (4H x IN)
                const float* __restrict__ whh,   // w_hh (4H x H)
                const float* __restrict__ bih,
                const float* __restrict__ bhh,
                const float* __restrict__ X,     // input trace, row t = input(t)
                float* __restrict__ Hout,        // (4097 x H), row (t+1) = h(t), row 0 zeroed
                float* __restrict__ out,         // d_out when LAST
                unsigned* __restrict__ bar)      // [0]=root, [16+16g]=group g
{
  constexpr int K   = IN + H;
  constexpr int KW  = K / SPLIT;        // K-range per wave
  constexpr int J   = KW / 64;          // weight regs per gate per lane
  constexpr int GSZ = NBLK / 8;         // blocks per barrier group
  static_assert(NBLK * 8 == H * SPLIT, "wave count must equal H*SPLIT");
  static_assert(KW % 64 == 0, "KW must be multiple of 64");

  const int tid  = threadIdx.x;
  const int lane = tid & 63;
  const int ws   = tid >> 6;                 // wave slot in block, 0..7
  const int gw   = blockIdx.x * 8 + ws;      // global wave id
  const int hid  = gw / SPLIT;               // owned h index
  const int half = gw % SPLIT;               // K-chunk (0 or 1)
  const int kw0  = half * KW;

  // ---- load weights into registers (static indices only) ----
  float w[4][J];
  #pragma unroll
  for (int g = 0; g < 4; ++g) {
    const size_t r = (size_t)g * H + hid;    // PyTorch gate order i,f,g,o
    #pragma unroll
    for (int j = 0; j < J; ++j) {
      const int kb = kw0 + 64 * j;           // wave-uniform (IN,KW multiples of 64)
      if (kb < IN) w[g][j] = win[r * IN + (kb + lane)];
      else         w[g][j] = whh[r * H  + (kb + lane - IN)];
    }
  }
  const float b0 = bih[0 * H + hid] + bhh[0 * H + hid];
  const float b1 = bih[1 * H + hid] + bhh[1 * H + hid];
  const float b2 = bih[2 * H + hid] + bhh[2 * H + hid];
  const float b3 = bih[3 * H + hid] + bhh[3 * H + hid];

  __shared__ float part[8][4];
  float c = 0.0f;

  const int grp = blockIdx.x / GSZ;
  unsigned* gcnt = bar + 16 + 16 * grp;
  unsigned* root = bar;

  for (int t = 0; t < NSTEP; ++t) {
    const float* __restrict__ xrow = X    + (size_t)t * IN;
    const float* __restrict__ hrow = Hout + (size_t)t * H;   // h(t-1)

    float xh[J];
    #pragma unroll
    for (int j = 0; j < J; ++j) {
      const int kb = kw0 + 64 * j;
      if (kb < IN) xh[j] = xrow[kb + lane];
      else         xh[j] = hrow[kb + lane - IN];
    }

    float a0 = 0.f, a1 = 0.f, a2 = 0.f, a3 = 0.f;
    #pragma unroll
    for (int j = 0; j < J; ++j) {
      a0 = fmaf(w[0][j], xh[j], a0);
      a1 = fmaf(w[1][j], xh[j], a1);
      a2 = fmaf(w[2][j], xh[j], a2);
      a3 = fmaf(w[3][j], xh[j], a3);
    }
    #pragma unroll
    for (int off = 32; off; off >>= 1) {     // all lanes end with full sums
      a0 += __shfl_xor(a0, off);
      a1 += __shfl_xor(a1, off);
      a2 += __shfl_xor(a2, off);
      a3 += __shfl_xor(a3, off);
    }

    if (SPLIT == 2) {                        // combine the two K-halves
      if (lane == 0) { part[ws][0] = a0; part[ws][1] = a1; part[ws][2] = a2; part[ws][3] = a3; }
      __syncthreads();
      if (half == 0) {
        a0 += part[ws ^ 1][0];
        a1 += part[ws ^ 1][1];
        a2 += part[ws ^ 1][2];
        a3 += part[ws ^ 1][3];
      }
    }

    if (SPLIT == 1 || half == 0) {
      const float gi = a0 + b0, gf = a1 + b1, gg = a2 + b2, go = a3 + b3;
      const float ig = 1.0f / (1.0f + expf(-gi));
      const float fg = 1.0f / (1.0f + expf(-gf));
      const float og = 1.0f / (1.0f + expf(-go));
      const float gt = tanhf(gg);
      c = fg * c + ig * gt;
      const float hn = og * tanhf(c);
      if (lane == 0) {
        Hout[(size_t)(t + 1) * H + hid] = hn;
        if (LAST) out[(size_t)t * H + hid] = hn;
      }
    }

    __syncthreads();   // all waves' stores drained to L2; protects part[] reuse
    if (tid == 0) {
      __builtin_amdgcn_fence(__ATOMIC_RELEASE, "agent");   // wbl2: stores -> LLC
      const unsigned a = __hip_atomic_fetch_add(gcnt, 1u, __ATOMIC_RELAXED,
                                                __HIP_MEMORY_SCOPE_AGENT);
      if (a == (unsigned)(t + 1) * (unsigned)GSZ - 1u)     // group-last this step
        __hip_atomic_fetch_add(root, 1u, __ATOMIC_RELAXED, __HIP_MEMORY_SCOPE_AGENT);
      const unsigned tgt = (unsigned)(t + 1) * 8u;
      while (__hip_atomic_load(root, __ATOMIC_RELAXED, __HIP_MEMORY_SCOPE_AGENT) < tgt)
        __builtin_amdgcn_s_sleep(2);
      __builtin_amdgcn_fence(__ATOMIC_ACQUIRE, "agent");   // inv L1+L2 for fresh h
    }
    __syncthreads();
  }
}

// ===================== Fallback: previous streaming path ====================
struct Params {
  const float* xn;
  const float* w_ih[4];
  const float* w_hh[4];
  const float* b_ih[4];
  const float* b_hh[4];
  float* h[4];
  float* c[4];
  float* out;
  int s;
};

__global__ __launch_bounds__(256) void step_kernel(Params p)
{
  const int lane = threadIdx.x & 63;
  const int W = blockIdx.x * 4 + (threadIdx.x >> 6);

  int layer, h, H, IN, t;
  if (W < 2048)      { layer = 0; h = W;        H = 2048; IN = 64;   t = p.s;     }
  else if (W < 3072) { layer = 1; h = W - 2048; H = 1024; IN = 2048; t = p.s - 1; }
  else if (W < 3584) { layer = 2; h = W - 3072; H = 512;  IN = 1024; t = p.s - 2; }
  else               { layer = 3; h = W - 3584; H = 256;  IN = 512;  t = p.s - 3; }
  if (t < 0 || t >= NSTEP) return;

  const float* xin;
  if (layer == 0) xin = p.xn + (size_t)t * 64;
  else            xin = p.h[layer - 1] + (size_t)(t & 1) * IN;
  const float* hprev = p.h[layer] + (size_t)((t + 1) & 1) * H;
  float*       hout  = p.h[layer] + (size_t)(t & 1) * H;
  const float* wih = p.w_ih[layer];
  const float* whh = p.w_hh[layer];

  float acc[4];
  #pragma unroll
  for (int g = 0; g < 4; ++g) {
    const size_t r = (size_t)g * H + h;
    const float* wi = wih + r * IN;
    const float* wh = whh + r * (size_t)H;
    float a = 0.0f;
    for (int k = lane; k < IN; k += 64) a += wi[k] * xin[k];
    for (int k = lane; k < H;  k += 64) a += wh[k] * hprev[k];
    acc[g] = a;
  }
  #pragma unroll
  for (int off = 32; off > 0; off >>= 1) {
    #pragma unroll
    for (int g = 0; g < 4; ++g) acc[g] += __shfl_down(acc[g], off);
  }
  if (lane == 0) {
    const float* bi = p.b_ih[layer];
    const float* bh = p.b_hh[layer];
    const float gi = acc[0] + bi[h]         + bh[h];
    const float gf = acc[1] + bi[H + h]     + bh[H + h];
    const float gg = acc[2] + bi[2 * H + h] + bh[2 * H + h];
    const float go = acc[3] + bi[3 * H + h] + bh[3 * H + h];
    const float ig = 1.0f / (1.0f + expf(-gi));
    const float fg = 1.0f / (1.0f + expf(-gf));
    const float og = 1.0f / (1.0f + expf(-go));
    const float gt = tanhf(gg);
    const float cn = fg * p.c[layer][h] + ig * gt;
    const float hn = og * tanhf(cn);
    p.c[layer][h] = cn;
    hout[h] = hn;
    if (layer == 3) p.out[(size_t)t * 256 + h] = hn;
  }
}

// ===================== host launch ==========================================
extern "C" void kernel_launch(void* const* d_in, const int* in_sizes, int n_in,
                              void* d_out, int out_size, void* d_ws, size_t ws_size,
                              hipStream_t stream)
{
  const float* x    = (const float*)d_in[0];
  const float* bn_w = (const float*)d_in[1];
  const float* bn_b = (const float*)d_in[2];
  const float* wih[4]; const float* whh[4]; const float* bih[4]; const float* bhh[4];
  for (int l = 0; l < 4; ++l) {
    wih[l] = (const float*)d_in[3 + 4 * l];
    whh[l] = (const float*)d_in[4 + 4 * l];
    bih[l] = (const float*)d_in[5 + 4 * l];
    bhh[l] = (const float*)d_in[6 + 4 * l];
  }
  float* out = (float*)d_out;

  // new-path workspace layout (floats, after a 4 KiB barrier region)
  const size_t XN  = (size_t)NSTEP * 64;
  const size_t NH1 = (size_t)(NSTEP + 1) * 2048;
  const size_t NH2 = (size_t)(NSTEP + 1) * 1024;
  const size_t NH3 = (size_t)(NSTEP + 1) * 512;
  const size_t NH4 = (size_t)(NSTEP + 1) * 256;
  const size_t need = 4096 + (XN + NH1 + NH2 + NH3 + NH4) * sizeof(float);

  if (ws_size >= need) {
    unsigned* bar = (unsigned*)d_ws;                  // 4 layers x 256 u32
    float* fb = (float*)((char*)d_ws + 4096);
    float* xn = fb;
    float* H1 = xn + XN;
    float* H2 = H1 + NH1;
    float* H3 = H2 + NH2;
    float* H4 = H3 + NH3;

    // re-init per call (graph-replay safe): barrier counters + zero rows 0
    hipMemsetAsync(bar, 0, 4096, stream);
    hipMemsetAsync(H1, 0, 2048 * sizeof(float), stream);
    hipMemsetAsync(H2, 0, 1024 * sizeof(float), stream);
    hipMemsetAsync(H3, 0,  512 * sizeof(float), stream);
    hipMemsetAsync(H4, 0,  256 * sizeof(float), stream);

    bn_kernel<<<1024, 256, 0, stream>>>(x, bn_w, bn_b, xn);

    lstm_layer<2048,   64, 1, 256, false><<<256, 512, 0, stream>>>(
        wih[0], whh[0], bih[0], bhh[0], xn,        H1, nullptr, bar + 0 * 256);
    lstm_layer<1024, 2048, 2, 256, false><<<256, 512, 0, stream>>>(
        wih[1], whh[1], bih[1], bhh[1], H1 + 2048, H2, nullptr, bar + 1 * 256);
    lstm_layer< 512, 1024, 1,  64, false><<< 64, 512, 0, stream>>>(
        wih[2], whh[2], bih[2], bhh[2], H2 + 1024, H3, nullptr, bar + 2 * 256);
    lstm_layer< 256,  512, 1,  32, true ><<< 32, 512, 0, stream>>>(
        wih[3], whh[3], bih[3], bhh[3], H3 + 512,  H4, out,     bar + 3 * 256);
    return;
  }

  // -------- fallback: previous passing streaming pipeline --------
  Params p;
  for (int l = 0; l < 4; ++l) { p.w_ih[l] = wih[l]; p.w_hh[l] = whh[l];
                                p.b_ih[l] = bih[l]; p.b_hh[l] = bhh[l]; }
  float* ws = (float*)d_ws;
  float* xn = ws;
  float* st = ws + (size_t)NSTEP * 64;
  p.xn = xn;
  const int Hs[4] = {2048, 1024, 512, 256};
  float* cur = st;
  for (int l = 0; l < 4; ++l) { p.h[l] = cur; cur += 2 * Hs[l]; }
  for (int l = 0; l < 4; ++l) { p.c[l] = cur; cur += Hs[l]; }
  p.out = out;

  const size_t state_bytes = (size_t)(cur - st) * sizeof(float);
  hipMemsetAsync(st, 0, state_bytes, stream);
  bn_kernel<<<1024, 256, 0, stream>>>(x, bn_w, bn_b, xn);
  for (int s = 0; s < NSTEP + 3; ++s) {
    p.s = s;
    step_kernel<<<960, 256, 0, stream>>>(p);
  }
}

// Round 6
// 92237.634 us; speedup vs baseline: 2.8134x; 1.1199x over previous
//
#include <hip/hip_runtime.h>
#include <cstddef>

#define NSTEP 4096
#define PIN(x) asm volatile("" : "+v"(x))

// ===================== BatchNorm over timestep channels =====================
__global__ __launch_bounds__(256) void bn_kernel(const float* __restrict__ x,
                                                 const float* __restrict__ bn_w,
                                                 const float* __restrict__ bn_b,
                                                 float* __restrict__ xn)
{
  const int t   = blockIdx.x;        // 0..1023
  const int tid = threadIdx.x;       // 256 = B*F
  const int b   = tid >> 6;
  const int f   = tid & 63;
  const float v = x[((size_t)b * 1024 + t) * 64 + f];
  float s = v, ss = v * v;
  #pragma unroll
  for (int off = 32; off > 0; off >>= 1) {
    s  += __shfl_down(s, off);
    ss += __shfl_down(ss, off);
  }
  __shared__ float sh[8];
  const int w = tid >> 6;
  if ((tid & 63) == 0) { sh[w] = s; sh[4 + w] = ss; }
  __syncthreads();
  const float S    = sh[0] + sh[1] + sh[2] + sh[3];
  const float SS   = sh[4] + sh[5] + sh[6] + sh[7];
  const float mean = S * (1.0f / 256.0f);
  const float var  = SS * (1.0f / 256.0f) - mean * mean;  // biased, matches jnp.var
  const float inv  = rsqrtf(var + 1e-5f);
  const float scale = bn_w[t] * inv;
  const float shift = bn_b[t] - mean * scale;
  xn[((size_t)b * 1024 + t) * 64 + f] = v * scale + shift;
}

// ===================== grid barrier (proven in round 4) =====================
// Two-level cumulative counter, 8 groups. Release fence -> group add; group
// last bumps root; poll root; acquire fence. __syncthreads() drains stores.
template<int NBLK>
__device__ __forceinline__ void grid_barrier(unsigned* __restrict__ bar,
                                             unsigned step1, int tid)
{
  constexpr unsigned GSZ = NBLK / 8;
  __syncthreads();
  if (tid == 0) {
    unsigned* gcnt = bar + 16 + 16 * (blockIdx.x / GSZ);
    unsigned* root = bar;
    __builtin_amdgcn_fence(__ATOMIC_RELEASE, "agent");
    const unsigned a = __hip_atomic_fetch_add(gcnt, 1u, __ATOMIC_RELAXED,
                                              __HIP_MEMORY_SCOPE_AGENT);
    if (a == step1 * GSZ - 1u)
      __hip_atomic_fetch_add(root, 1u, __ATOMIC_RELAXED, __HIP_MEMORY_SCOPE_AGENT);
    const unsigned tgt = step1 * 8u;
    while (__hip_atomic_load(root, __ATOMIC_RELAXED, __HIP_MEMORY_SCOPE_AGENT) < tgt)
      __builtin_amdgcn_s_sleep(2);
    __builtin_amdgcn_fence(__ATOMIC_ACQUIRE, "agent");
  }
  __syncthreads();
}

// ===================== wave helpers =========================================
__device__ __forceinline__ void reduce4(float& a0, float& a1, float& a2, float& a3)
{
  #pragma unroll
  for (int off = 32; off; off >>= 1) {
    a0 += __shfl_xor(a0, off);
    a1 += __shfl_xor(a1, off);
    a2 += __shfl_xor(a2, off);
    a3 += __shfl_xor(a3, off);
  }
}

__device__ __forceinline__ float lstm_act(float a0, float a1, float a2, float a3,
                                          const float* bsum, float& c)
{
  const float gi = a0 + bsum[0], gf = a1 + bsum[1];
  const float gg = a2 + bsum[2], go = a3 + bsum[3];
  const float ig = 1.0f / (1.0f + expf(-gi));
  const float fg = 1.0f / (1.0f + expf(-gf));
  const float og = 1.0f / (1.0f + expf(-go));
  c = fg * c + ig * tanhf(gg);
  return og * tanhf(c);
}

// ===================== Layer 1: W_ih (4 regs) + W_hh (128 regs) resident ====
__global__ __launch_bounds__(512, 2)
void lstm_l1(const float* __restrict__ win, const float* __restrict__ whh,
             const float* __restrict__ bih, const float* __restrict__ bhh,
             const float* __restrict__ X,     // (4096,64) normalized input
             float* __restrict__ Hout,        // (4097,2048), row r = h(r-1)
             unsigned* __restrict__ bar)
{
  constexpr int H = 2048, J4 = H / 256;       // 8 float4 per gate
  const int tid = threadIdx.x, lane = tid & 63, wsl = tid >> 6;
  const int hid = blockIdx.x * 8 + wsl;       // 2048 waves == H

  float  wi[4];
  float4 w[4][J4];
  float  bsum[4];
  #pragma unroll
  for (int g = 0; g < 4; ++g) {
    const size_t r = (size_t)g * H + hid;     // PyTorch gate order i,f,g,o
    wi[g] = win[r * 64 + lane];
    PIN(wi[g]);
    const float4* wrow = (const float4*)(whh + r * (size_t)H);
    #pragma unroll
    for (int j = 0; j < J4; ++j) {
      w[g][j] = wrow[j * 64 + lane];
      PIN(w[g][j].x); PIN(w[g][j].y); PIN(w[g][j].z); PIN(w[g][j].w);
    }
    bsum[g] = bih[r] + bhh[r];
    PIN(bsum[g]);
  }
  float c = 0.0f;

  #pragma unroll 1
  for (int t = 0; t < NSTEP; ++t) {
    const float xv = X[(size_t)t * 64 + lane];
    const float4* hrow = (const float4*)(Hout + (size_t)t * H);   // h(t-1)
    float a0 = wi[0] * xv, a1 = wi[1] * xv, a2 = wi[2] * xv, a3 = wi[3] * xv;
    #pragma unroll
    for (int j = 0; j < J4; ++j) {
      const float4 hv = hrow[j * 64 + lane];
      a0 = fmaf(w[0][j].x, hv.x, a0); a0 = fmaf(w[0][j].y, hv.y, a0);
      a0 = fmaf(w[0][j].z, hv.z, a0); a0 = fmaf(w[0][j].w, hv.w, a0);
      a1 = fmaf(w[1][j].x, hv.x, a1); a1 = fmaf(w[1][j].y, hv.y, a1);
      a1 = fmaf(w[1][j].z, hv.z, a1); a1 = fmaf(w[1][j].w, hv.w, a1);
      a2 = fmaf(w[2][j].x, hv.x, a2); a2 = fmaf(w[2][j].y, hv.y, a2);
      a2 = fmaf(w[2][j].z, hv.z, a2); a2 = fmaf(w[2][j].w, hv.w, a2);
      a3 = fmaf(w[3][j].x, hv.x, a3); a3 = fmaf(w[3][j].y, hv.y, a3);
      a3 = fmaf(w[3][j].z, hv.z, a3); a3 = fmaf(w[3][j].w, hv.w, a3);
    }
    reduce4(a0, a1, a2, a3);
    const float hn = lstm_act(a0, a1, a2, a3, bsum, c);
    if (lane == 0) Hout[(size_t)(t + 1) * H + hid] = hn;
    grid_barrier<256>(bar, (unsigned)(t + 1), tid);
  }
}

// ===================== fused L2+L3+L4 (pipelined, one barrier/step) =========
// One step of a layer with both W_ih and W_hh resident in w[] (4*JT float4).
template<int IN, int H, int JT, bool LAST>
__device__ __forceinline__ void lstm_step(const float4* __restrict__ w,
                                          const float* __restrict__ bsum,
                                          float& c, int lane, int hid, int t,
                                          const float* __restrict__ X,     // row t = input(t), stride IN
                                          float* __restrict__ Hout,        // row r = h(r-1), stride H
                                          float* __restrict__ out)
{
  constexpr int JI = IN / 256, JH = H / 256;
  static_assert(JI + JH == JT, "JT mismatch");
  const float4* xrow = (const float4*)(X    + (size_t)t * IN);
  const float4* hrow = (const float4*)(Hout + (size_t)t * H);
  float a0 = 0.f, a1 = 0.f, a2 = 0.f, a3 = 0.f;
  #pragma unroll
  for (int j = 0; j < JI; ++j) {
    const float4 v = xrow[j * 64 + lane];
    a0 = fmaf(w[0*JT+j].x, v.x, a0); a0 = fmaf(w[0*JT+j].y, v.y, a0);
    a0 = fmaf(w[0*JT+j].z, v.z, a0); a0 = fmaf(w[0*JT+j].w, v.w, a0);
    a1 = fmaf(w[1*JT+j].x, v.x, a1); a1 = fmaf(w[1*JT+j].y, v.y, a1);
    a1 = fmaf(w[1*JT+j].z, v.z, a1); a1 = fmaf(w[1*JT+j].w, v.w, a1);
    a2 = fmaf(w[2*JT+j].x, v.x, a2); a2 = fmaf(w[2*JT+j].y, v.y, a2);
    a2 = fmaf(w[2*JT+j].z, v.z, a2); a2 = fmaf(w[2*JT+j].w, v.w, a2);
    a3 = fmaf(w[3*JT+j].x, v.x, a3); a3 = fmaf(w[3*JT+j].y, v.y, a3);
    a3 = fmaf(w[3*JT+j].z, v.z, a3); a3 = fmaf(w[3*JT+j].w, v.w, a3);
  }
  #pragma unroll
  for (int j = 0; j < JH; ++j) {
    const float4 v = hrow[j * 64 + lane];
    a0 = fmaf(w[0*JT+JI+j].x, v.x, a0); a0 = fmaf(w[0*JT+JI+j].y, v.y, a0);
    a0 = fmaf(w[0*JT+JI+j].z, v.z, a0); a0 = fmaf(w[0*JT+JI+j].w, v.w, a0);
    a1 = fmaf(w[1*JT+JI+j].x, v.x, a1); a1 = fmaf(w[1*JT+JI+j].y, v.y, a1);
    a1 = fmaf(w[1*JT+JI+j].z, v.z, a1); a1 = fmaf(w[1*JT+JI+j].w, v.w, a1);
    a2 = fmaf(w[2*JT+JI+j].x, v.x, a2); a2 = fmaf(w[2*JT+JI+j].y, v.y, a2);
    a2 = fmaf(w[2*JT+JI+j].z, v.z, a2); a2 = fmaf(w[2*JT+JI+j].w, v.w, a2);
    a3 = fmaf(w[3*JT+JI+j].x, v.x, a3); a3 = fmaf(w[3*JT+JI+j].y, v.y, a3);
    a3 = fmaf(w[3*JT+JI+j].z, v.z, a3); a3 = fmaf(w[3*JT+JI+j].w, v.w, a3);
  }
  reduce4(a0, a1, a2, a3);
  const float hn = lstm_act(a0, a1, a2, a3, bsum, c);
  if (lane == 0) {
    Hout[(size_t)(t + 1) * H + hid] = hn;
    if (LAST) out[(size_t)t * 256 + hid] = hn;
  }
}

__global__ __launch_bounds__(512, 2)
void lstm_l234(const float* __restrict__ win2, const float* __restrict__ whh2,
               const float* __restrict__ bih2, const float* __restrict__ bhh2,
               const float* __restrict__ win3, const float* __restrict__ whh3,
               const float* __restrict__ bih3, const float* __restrict__ bhh3,
               const float* __restrict__ win4, const float* __restrict__ whh4,
               const float* __restrict__ bih4, const float* __restrict__ bhh4,
               const float* __restrict__ X2,   // = H1 + 2048 (row t = h1(t))
               float* __restrict__ H2t, float* __restrict__ H3t,
               float* __restrict__ H4t, float* __restrict__ out,
               unsigned* __restrict__ bar)
{
  const int tid = threadIdx.x, lane = tid & 63, wsl = tid >> 6;
  const int gw = blockIdx.x * 8 + wsl;        // 0..1791

  // unioned weight storage: L2 uses 48 float4, L3 24, L4 12
  float4 w[48];
  float  bsum[4];
  #pragma unroll
  for (int i = 0; i < 48; ++i) w[i] = make_float4(0.f, 0.f, 0.f, 0.f);

  int hid;
  if (gw < 1024) {                            // L2: IN=2048 H=1024, JT=12
    hid = gw;
    #pragma unroll
    for (int g = 0; g < 4; ++g) {
      const size_t r = (size_t)g * 1024 + hid;
      const float4* wi = (const float4*)(win2 + r * 2048);
      const float4* wh = (const float4*)(whh2 + r * 1024);
      #pragma unroll
      for (int j = 0; j < 8; ++j) w[g * 12 + j]     = wi[j * 64 + lane];
      #pragma unroll
      for (int j = 0; j < 4; ++j) w[g * 12 + 8 + j] = wh[j * 64 + lane];
      bsum[g] = bih2[r] + bhh2[r];
    }
  } else if (gw < 1536) {                     // L3: IN=1024 H=512, JT=6
    hid = gw - 1024;
    #pragma unroll
    for (int g = 0; g < 4; ++g) {
      const size_t r = (size_t)g * 512 + hid;
      const float4* wi = (const float4*)(win3 + r * 1024);
      const float4* wh = (const float4*)(whh3 + r * 512);
      #pragma unroll
      for (int j = 0; j < 4; ++j) w[g * 6 + j]     = wi[j * 64 + lane];
      #pragma unroll
      for (int j = 0; j < 2; ++j) w[g * 6 + 4 + j] = wh[j * 64 + lane];
      bsum[g] = bih3[r] + bhh3[r];
    }
  } else {                                    // L4: IN=512 H=256, JT=3
    hid = gw - 1536;
    #pragma unroll
    for (int g = 0; g < 4; ++g) {
      const size_t r = (size_t)g * 256 + hid;
      const float4* wi = (const float4*)(win4 + r * 512);
      const float4* wh = (const float4*)(whh4 + r * 256);
      #pragma unroll
      for (int j = 0; j < 2; ++j) w[g * 3 + j]     = wi[j * 64 + lane];
      w[g * 3 + 2] = wh[lane];
      bsum[g] = bih4[r] + bhh4[r];
    }
  }
  #pragma unroll
  for (int i = 0; i < 48; ++i) { PIN(w[i].x); PIN(w[i].y); PIN(w[i].z); PIN(w[i].w); }
  #pragma unroll
  for (int g = 0; g < 4; ++g) PIN(bsum[g]);

  float c = 0.0f;

  #pragma unroll 1
  for (int s = 0; s < NSTEP + 2; ++s) {
    if (gw < 1024) {
      if (s < NSTEP)
        lstm_step<2048, 1024, 12, false>(w, bsum, c, lane, hid, s, X2, H2t, nullptr);
    } else if (gw < 1536) {
      if (s >= 1 && s <= NSTEP)
        lstm_step<1024, 512, 6, false>(w, bsum, c, lane, hid, s - 1, H2t + 1024, H3t, nullptr);
    } else {
      if (s >= 2)
        lstm_step<512, 256, 3, true>(w, bsum, c, lane, hid, s - 2, H3t + 512, H4t, out);
    }
    grid_barrier<224>(bar, (unsigned)(s + 1), tid);
  }
}

// ===================== Fallback: round-1 streaming path =====================
struct Params {
  const float* xn;
  const float* w_ih[4];
  const float* w_hh[4];
  const float* b_ih[4];
  const float* b_hh[4];
  float* h[4];
  float* c[4];
  float* out;
  int s;
};

__global__ __launch_bounds__(256) void step_kernel(Params p)
{
  const int lane = threadIdx.x & 63;
  const int W = blockIdx.x * 4 + (threadIdx.x >> 6);

  int layer, h, H, IN, t;
  if (W < 2048)      { layer = 0; h = W;        H = 2048; IN = 64;   t = p.s;     }
  else if (W < 3072) { layer = 1; h = W - 2048; H = 1024; IN = 2048; t = p.s - 1; }
  else if (W < 3584) { layer = 2; h = W - 3072; H = 512;  IN = 1024; t = p.s - 2; }
  else               { layer = 3; h = W - 3584; H = 256;  IN = 512;  t = p.s - 3; }
  if (t < 0 || t >= NSTEP) return;

  const float* xin;
  if (layer == 0) xin = p.xn + (size_t)t * 64;
  else            xin = p.h[layer - 1] + (size_t)(t & 1) * IN;
  const float* hprev = p.h[layer] + (size_t)((t + 1) & 1) * H;
  float*       hout  = p.h[layer] + (size_t)(t & 1) * H;
  const float* wih = p.w_ih[layer];
  const float* whh = p.w_hh[layer];

  float acc[4];
  #pragma unroll
  for (int g = 0; g < 4; ++g) {
    const size_t r = (size_t)g * H + h;
    const float* wi = wih + r * IN;
    const float* wh = whh + r * (size_t)H;
    float a = 0.0f;
    for (int k = lane; k < IN; k += 64) a += wi[k] * xin[k];
    for (int k = lane; k < H;  k += 64) a += wh[k] * hprev[k];
    acc[g] = a;
  }
  #pragma unroll
  for (int off = 32; off > 0; off >>= 1) {
    #pragma unroll
    for (int g = 0; g < 4; ++g) acc[g] += __shfl_down(acc[g], off);
  }
  if (lane == 0) {
    const float* bi = p.b_ih[layer];
    const float* bh = p.b_hh[layer];
    const float gi = acc[0] + bi[h]         + bh[h];
    const float gf = acc[1] + bi[H + h]     + bh[H + h];
    const float gg = acc[2] + bi[2 * H + h] + bh[2 * H + h];
    const float go = acc[3] + bi[3 * H + h] + bh[3 * H + h];
    const float ig = 1.0f / (1.0f + expf(-gi));
    const float fg = 1.0f / (1.0f + expf(-gf));
    const float og = 1.0f / (1.0f + expf(-go));
    const float gt = tanhf(gg);
    const float cn = fg * p.c[layer][h] + ig * gt;
    const float hn = og * tanhf(cn);
    p.c[layer][h] = cn;
    hout[h] = hn;
    if (layer == 3) p.out[(size_t)t * 256 + h] = hn;
  }
}

// ===================== host launch ==========================================
extern "C" void kernel_launch(void* const* d_in, const int* in_sizes, int n_in,
                              void* d_out, int out_size, void* d_ws, size_t ws_size,
                              hipStream_t stream)
{
  const float* x    = (const float*)d_in[0];
  const float* bn_w = (const float*)d_in[1];
  const float* bn_b = (const float*)d_in[2];
  const float* wih[4]; const float* whh[4]; const float* bih[4]; const float* bhh[4];
  for (int l = 0; l < 4; ++l) {
    wih[l] = (const float*)d_in[3 + 4 * l];
    whh[l] = (const float*)d_in[4 + 4 * l];
    bih[l] = (const float*)d_in[5 + 4 * l];
    bhh[l] = (const float*)d_in[6 + 4 * l];
  }
  float* out = (float*)d_out;

  const size_t XN  = (size_t)NSTEP * 64;
  const size_t NH1 = (size_t)(NSTEP + 1) * 2048;
  const size_t NH2 = (size_t)(NSTEP + 1) * 1024;
  const size_t NH3 = (size_t)(NSTEP + 1) * 512;
  const size_t NH4 = (size_t)(NSTEP + 1) * 256;
  const size_t need = 4096 + (XN + NH1 + NH2 + NH3 + NH4) * sizeof(float);

  if (ws_size >= need) {
    unsigned* bar = (unsigned*)d_ws;               // 1024 u32: [0..255]=L1, [256..511]=fused
    float* fb = (float*)((char*)d_ws + 4096);
    float* xn = fb;
    float* H1 = xn + XN;
    float* H2 = H1 + NH1;
    float* H3 = H2 + NH2;
    float* H4 = H3 + NH3;

    hipMemsetAsync(bar, 0, 4096, stream);
    hipMemsetAsync(H1, 0, 2048 * sizeof(float), stream);
    hipMemsetAsync(H2, 0, 1024 * sizeof(float), stream);
    hipMemsetAsync(H3, 0,  512 * sizeof(float), stream);
    hipMemsetAsync(H4, 0,  256 * sizeof(float), stream);

    bn_kernel<<<1024, 256, 0, stream>>>(x, bn_w, bn_b, xn);

    lstm_l1<<<256, 512, 0, stream>>>(wih[0], whh[0], bih[0], bhh[0],
                                     xn, H1, bar);

    lstm_l234<<<224, 512, 0, stream>>>(wih[1], whh[1], bih[1], bhh[1],
                                       wih[2], whh[2], bih[2], bhh[2],
                                       wih[3], whh[3], bih[3], bhh[3],
                                       H1 + 2048, H2, H3, H4, out, bar + 256);
    return;
  }

  // -------- fallback: streaming pipeline (proven) --------
  Params p;
  for (int l = 0; l < 4; ++l) { p.w_ih[l] = wih[l]; p.w_hh[l] = whh[l];
                                p.b_ih[l] = bih[l]; p.b_hh[l] = bhh[l]; }
  float* ws = (float*)d_ws;
  float* xn = ws;
  float* st = ws + (size_t)NSTEP * 64;
  p.xn = xn;
  const int Hs[4] = {2048, 1024, 512, 256};
  float* cur = st;
  for (int l = 0; l < 4; ++l) { p.h[l] = cur; cur += 2 * Hs[l]; }
  for (int l = 0; l < 4; ++l) { p.c[l] = cur; cur += Hs[l]; }
  p.out = out;

  const size_t state_bytes = (size_t)(cur - st) * sizeof(float);
  hipMemsetAsync(st, 0, state_bytes, stream);
  bn_kernel<<<1024, 256, 0, stream>>>(x, bn_w, bn_b, xn);
  for (int s = 0; s < NSTEP + 3; ++s) {
    p.s = s;
    step_kernel<<<960, 256, 0, stream>>>(p);
  }
}

// Round 7
// 91523.260 us; speedup vs baseline: 2.8353x; 1.0078x over previous
//
#include <hip/hip_runtime.h>
#include <cstddef>

#define NSTEP 4096
#define PIN(x) asm volatile("" : "+v"(x))

// ===================== BatchNorm over timestep channels =====================
__global__ __launch_bounds__(256) void bn_kernel(const float* __restrict__ x,
                                                 const float* __restrict__ bn_w,
                                                 const float* __restrict__ bn_b,
                                                 float* __restrict__ xn)
{
  const int t   = blockIdx.x;        // 0..1023
  const int tid = threadIdx.x;       // 256 = B*F
  const int b   = tid >> 6;
  const int f   = tid & 63;
  const float v = x[((size_t)b * 1024 + t) * 64 + f];
  float s = v, ss = v * v;
  #pragma unroll
  for (int off = 32; off > 0; off >>= 1) {
    s  += __shfl_down(s, off);
    ss += __shfl_down(ss, off);
  }
  __shared__ float sh[8];
  const int w = tid >> 6;
  if ((tid & 63) == 0) { sh[w] = s; sh[4 + w] = ss; }
  __syncthreads();
  const float S    = sh[0] + sh[1] + sh[2] + sh[3];
  const float SS   = sh[4] + sh[5] + sh[6] + sh[7];
  const float mean = S * (1.0f / 256.0f);
  const float var  = SS * (1.0f / 256.0f) - mean * mean;  // biased, matches jnp.var
  const float inv  = rsqrtf(var + 1e-5f);
  const float scale = bn_w[t] * inv;
  const float shift = bn_b[t] - mean * scale;
  xn[((size_t)b * 1024 + t) * 64 + f] = v * scale + shift;
}

// ===================== grid barrier (proven in rounds 4-6) ==================
// Two-level cumulative counter, 8 groups. Release fence -> group add; group
// last bumps root; poll root; acquire fence. __syncthreads() drains stores.
template<int NBLK>
__device__ __forceinline__ void grid_barrier(unsigned* __restrict__ bar,
                                             unsigned step1, int tid)
{
  constexpr unsigned GSZ = NBLK / 8;
  __syncthreads();
  if (tid == 0) {
    unsigned* gcnt = bar + 16 + 16 * (blockIdx.x / GSZ);
    unsigned* root = bar;
    __builtin_amdgcn_fence(__ATOMIC_RELEASE, "agent");
    const unsigned a = __hip_atomic_fetch_add(gcnt, 1u, __ATOMIC_RELAXED,
                                              __HIP_MEMORY_SCOPE_AGENT);
    if (a == step1 * GSZ - 1u)
      __hip_atomic_fetch_add(root, 1u, __ATOMIC_RELAXED, __HIP_MEMORY_SCOPE_AGENT);
    const unsigned tgt = step1 * 8u;
    while (__hip_atomic_load(root, __ATOMIC_RELAXED, __HIP_MEMORY_SCOPE_AGENT) < tgt)
      __builtin_amdgcn_s_sleep(2);
    __builtin_amdgcn_fence(__ATOMIC_ACQUIRE, "agent");
  }
  __syncthreads();
}

// ===================== wave helpers =========================================
__device__ __forceinline__ void reduce4(float& a0, float& a1, float& a2, float& a3)
{
  #pragma unroll
  for (int off = 32; off; off >>= 1) {
    a0 += __shfl_xor(a0, off);
    a1 += __shfl_xor(a1, off);
    a2 += __shfl_xor(a2, off);
    a3 += __shfl_xor(a3, off);
  }
}

__device__ __forceinline__ float lstm_act(float a0, float a1, float a2, float a3,
                                          const float* bsum, float& c)
{
  const float gi = a0 + bsum[0], gf = a1 + bsum[1];
  const float gg = a2 + bsum[2], go = a3 + bsum[3];
  const float ig = 1.0f / (1.0f + expf(-gi));
  const float fg = 1.0f / (1.0f + expf(-gf));
  const float og = 1.0f / (1.0f + expf(-go));
  c = fg * c + ig * tanhf(gg);
  return og * tanhf(c);
}

// ===================== Layer 1: W_ih (4 regs) + W_hh (128 regs) resident ====
// __launch_bounds__(512, 1): 1 block/CU -> 2 waves/SIMD -> VGPR cap 256.
// (512,2) was interpreted as 2 blocks/CU -> cap 128 -> weights spilled.
__global__ __launch_bounds__(512, 1)
void lstm_l1(const float* __restrict__ win, const float* __restrict__ whh,
             const float* __restrict__ bih, const float* __restrict__ bhh,
             const float* __restrict__ X,     // (4096,64) normalized input
             float* __restrict__ Hout,        // (4097,2048), row r = h(r-1)
             unsigned* __restrict__ bar)
{
  constexpr int H = 2048, J4 = H / 256;       // 8 float4 per gate
  const int tid = threadIdx.x, lane = tid & 63, wsl = tid >> 6;
  const int hid = blockIdx.x * 8 + wsl;       // 2048 waves == H

  float  wi[4];
  float4 w[4][J4];
  float  bsum[4];
  #pragma unroll
  for (int g = 0; g < 4; ++g) {
    const size_t r = (size_t)g * H + hid;     // PyTorch gate order i,f,g,o
    wi[g] = win[r * 64 + lane];
    PIN(wi[g]);
    const float4* wrow = (const float4*)(whh + r * (size_t)H);
    #pragma unroll
    for (int j = 0; j < J4; ++j) {
      w[g][j] = wrow[j * 64 + lane];
      PIN(w[g][j].x); PIN(w[g][j].y); PIN(w[g][j].z); PIN(w[g][j].w);
    }
    bsum[g] = bih[r] + bhh[r];
    PIN(bsum[g]);
  }
  float c = 0.0f;

  #pragma unroll 1
  for (int t = 0; t < NSTEP; ++t) {
    const float xv = X[(size_t)t * 64 + lane];
    const float4* hrow = (const float4*)(Hout + (size_t)t * H);   // h(t-1)
    float a0 = wi[0] * xv, a1 = wi[1] * xv, a2 = wi[2] * xv, a3 = wi[3] * xv;
    #pragma unroll
    for (int j = 0; j < J4; ++j) {
      const float4 hv = hrow[j * 64 + lane];
      a0 = fmaf(w[0][j].x, hv.x, a0); a0 = fmaf(w[0][j].y, hv.y, a0);
      a0 = fmaf(w[0][j].z, hv.z, a0); a0 = fmaf(w[0][j].w, hv.w, a0);
      a1 = fmaf(w[1][j].x, hv.x, a1); a1 = fmaf(w[1][j].y, hv.y, a1);
      a1 = fmaf(w[1][j].z, hv.z, a1); a1 = fmaf(w[1][j].w, hv.w, a1);
      a2 = fmaf(w[2][j].x, hv.x, a2); a2 = fmaf(w[2][j].y, hv.y, a2);
      a2 = fmaf(w[2][j].z, hv.z, a2); a2 = fmaf(w[2][j].w, hv.w, a2);
      a3 = fmaf(w[3][j].x, hv.x, a3); a3 = fmaf(w[3][j].y, hv.y, a3);
      a3 = fmaf(w[3][j].z, hv.z, a3); a3 = fmaf(w[3][j].w, hv.w, a3);
    }
    reduce4(a0, a1, a2, a3);
    const float hn = lstm_act(a0, a1, a2, a3, bsum, c);
    if (lane == 0) Hout[(size_t)(t + 1) * H + hid] = hn;
    grid_barrier<256>(bar, (unsigned)(t + 1), tid);
  }
}

// ===================== fused L2+L3+L4 (pipelined, one barrier/step) =========
// One step of a layer with both W_ih and W_hh resident in w[] (4*JT float4).
template<int IN, int H, int JT, bool LAST>
__device__ __forceinline__ void lstm_step(const float4* __restrict__ w,
                                          const float* __restrict__ bsum,
                                          float& c, int lane, int hid, int t,
                                          const float* __restrict__ X,     // row t = input(t), stride IN
                                          float* __restrict__ Hout,        // row r = h(r-1), stride H
                                          float* __restrict__ out)
{
  constexpr int JI = IN / 256, JH = H / 256;
  static_assert(JI + JH == JT, "JT mismatch");
  const float4* xrow = (const float4*)(X    + (size_t)t * IN);
  const float4* hrow = (const float4*)(Hout + (size_t)t * H);
  float a0 = 0.f, a1 = 0.f, a2 = 0.f, a3 = 0.f;
  #pragma unroll
  for (int j = 0; j < JI; ++j) {
    const float4 v = xrow[j * 64 + lane];
    a0 = fmaf(w[0*JT+j].x, v.x, a0); a0 = fmaf(w[0*JT+j].y, v.y, a0);
    a0 = fmaf(w[0*JT+j].z, v.z, a0); a0 = fmaf(w[0*JT+j].w, v.w, a0);
    a1 = fmaf(w[1*JT+j].x, v.x, a1); a1 = fmaf(w[1*JT+j].y, v.y, a1);
    a1 = fmaf(w[1*JT+j].z, v.z, a1); a1 = fmaf(w[1*JT+j].w, v.w, a1);
    a2 = fmaf(w[2*JT+j].x, v.x, a2); a2 = fmaf(w[2*JT+j].y, v.y, a2);
    a2 = fmaf(w[2*JT+j].z, v.z, a2); a2 = fmaf(w[2*JT+j].w, v.w, a2);
    a3 = fmaf(w[3*JT+j].x, v.x, a3); a3 = fmaf(w[3*JT+j].y, v.y, a3);
    a3 = fmaf(w[3*JT+j].z, v.z, a3); a3 = fmaf(w[3*JT+j].w, v.w, a3);
  }
  #pragma unroll
  for (int j = 0; j < JH; ++j) {
    const float4 v = hrow[j * 64 + lane];
    a0 = fmaf(w[0*JT+JI+j].x, v.x, a0); a0 = fmaf(w[0*JT+JI+j].y, v.y, a0);
    a0 = fmaf(w[0*JT+JI+j].z, v.z, a0); a0 = fmaf(w[0*JT+JI+j].w, v.w, a0);
    a1 = fmaf(w[1*JT+JI+j].x, v.x, a1); a1 = fmaf(w[1*JT+JI+j].y, v.y, a1);
    a1 = fmaf(w[1*JT+JI+j].z, v.z, a1); a1 = fmaf(w[1*JT+JI+j].w, v.w, a1);
    a2 = fmaf(w[2*JT+JI+j].x, v.x, a2); a2 = fmaf(w[2*JT+JI+j].y, v.y, a2);
    a2 = fmaf(w[2*JT+JI+j].z, v.z, a2); a2 = fmaf(w[2*JT+JI+j].w, v.w, a2);
    a3 = fmaf(w[3*JT+JI+j].x, v.x, a3); a3 = fmaf(w[3*JT+JI+j].y, v.y, a3);
    a3 = fmaf(w[3*JT+JI+j].z, v.z, a3); a3 = fmaf(w[3*JT+JI+j].w, v.w, a3);
  }
  reduce4(a0, a1, a2, a3);
  const float hn = lstm_act(a0, a1, a2, a3, bsum, c);
  if (lane == 0) {
    Hout[(size_t)(t + 1) * H + hid] = hn;
    if (LAST) out[(size_t)t * 256 + hid] = hn;
  }
}

__global__ __launch_bounds__(512, 1)
void lstm_l234(const float* __restrict__ win2, const float* __restrict__ whh2,
               const float* __restrict__ bih2, const float* __restrict__ bhh2,
               const float* __restrict__ win3, const float* __restrict__ whh3,
               const float* __restrict__ bih3, const float* __restrict__ bhh3,
               const float* __restrict__ win4, const float* __restrict__ whh4,
               const float* __restrict__ bih4, const float* __restrict__ bhh4,
               const float* __restrict__ X2,   // = H1 + 2048 (row t = h1(t))
               float* __restrict__ H2t, float* __restrict__ H3t,
               float* __restrict__ H4t, float* __restrict__ out,
               unsigned* __restrict__ bar)
{
  const int tid = threadIdx.x, lane = tid & 63, wsl = tid >> 6;
  const int gw = blockIdx.x * 8 + wsl;        // 0..1791

  // unioned weight storage: L2 uses 48 float4, L3 24, L4 12
  float4 w[48];
  float  bsum[4];
  #pragma unroll
  for (int i = 0; i < 48; ++i) w[i] = make_float4(0.f, 0.f, 0.f, 0.f);

  int hid;
  if (gw < 1024) {                            // L2: IN=2048 H=1024, JT=12
    hid = gw;
    #pragma unroll
    for (int g = 0; g < 4; ++g) {
      const size_t r = (size_t)g * 1024 + hid;
      const float4* wi = (const float4*)(win2 + r * 2048);
      const float4* wh = (const float4*)(whh2 + r * 1024);
      #pragma unroll
      for (int j = 0; j < 8; ++j) w[g * 12 + j]     = wi[j * 64 + lane];
      #pragma unroll
      for (int j = 0; j < 4; ++j) w[g * 12 + 8 + j] = wh[j * 64 + lane];
      bsum[g] = bih2[r] + bhh2[r];
    }
  } else if (gw < 1536) {                     // L3: IN=1024 H=512, JT=6
    hid = gw - 1024;
    #pragma unroll
    for (int g = 0; g < 4; ++g) {
      const size_t r = (size_t)g * 512 + hid;
      const float4* wi = (const float4*)(win3 + r * 1024);
      const float4* wh = (const float4*)(whh3 + r * 512);
      #pragma unroll
      for (int j = 0; j < 4; ++j) w[g * 6 + j]     = wi[j * 64 + lane];
      #pragma unroll
      for (int j = 0; j < 2; ++j) w[g * 6 + 4 + j] = wh[j * 64 + lane];
      bsum[g] = bih3[r] + bhh3[r];
    }
  } else {                                    // L4: IN=512 H=256, JT=3
    hid = gw - 1536;
    #pragma unroll
    for (int g = 0; g < 4; ++g) {
      const size_t r = (size_t)g * 256 + hid;
      const float4* wi = (const float4*)(win4 + r * 512);
      const float4* wh = (const float4*)(whh4 + r * 256);
      #pragma unroll
      for (int j = 0; j < 2; ++j) w[g * 3 + j]     = wi[j * 64 + lane];
      w[g * 3 + 2] = wh[lane];
      bsum[g] = bih4[r] + bhh4[r];
    }
  }
  #pragma unroll
  for (int i = 0; i < 48; ++i) { PIN(w[i].x); PIN(w[i].y); PIN(w[i].z); PIN(w[i].w); }
  #pragma unroll
  for (int g = 0; g < 4; ++g) PIN(bsum[g]);

  float c = 0.0f;

  #pragma unroll 1
  for (int s = 0; s < NSTEP + 2; ++s) {
    if (gw < 1024) {
      if (s < NSTEP)
        lstm_step<2048, 1024, 12, false>(w, bsum, c, lane, hid, s, X2, H2t, nullptr);
    } else if (gw < 1536) {
      if (s >= 1 && s <= NSTEP)
        lstm_step<1024, 512, 6, false>(w, bsum, c, lane, hid, s - 1, H2t + 1024, H3t, nullptr);
    } else {
      if (s >= 2)
        lstm_step<512, 256, 3, true>(w, bsum, c, lane, hid, s - 2, H3t + 512, H4t, out);
    }
    grid_barrier<224>(bar, (unsigned)(s + 1), tid);
  }
}

// ===================== Fallback: round-1 streaming path =====================
struct Params {
  const float* xn;
  const float* w_ih[4];
  const float* w_hh[4];
  const float* b_ih[4];
  const float* b_hh[4];
  float* h[4];
  float* c[4];
  float* out;
  int s;
};

__global__ __launch_bounds__(256) void step_kernel(Params p)
{
  const int lane = threadIdx.x & 63;
  const int W = blockIdx.x * 4 + (threadIdx.x >> 6);

  int layer, h, H, IN, t;
  if (W < 2048)      { layer = 0; h = W;        H = 2048; IN = 64;   t = p.s;     }
  else if (W < 3072) { layer = 1; h = W - 2048; H = 1024; IN = 2048; t = p.s - 1; }
  else if (W < 3584) { layer = 2; h = W - 3072; H = 512;  IN = 1024; t = p.s - 2; }
  else               { layer = 3; h = W - 3584; H = 256;  IN = 512;  t = p.s - 3; }
  if (t < 0 || t >= NSTEP) return;

  const float* xin;
  if (layer == 0) xin = p.xn + (size_t)t * 64;
  else            xin = p.h[layer - 1] + (size_t)(t & 1) * IN;
  const float* hprev = p.h[layer] + (size_t)((t + 1) & 1) * H;
  float*       hout  = p.h[layer] + (size_t)(t & 1) * H;
  const float* wih = p.w_ih[layer];
  const float* whh = p.w_hh[layer];

  float acc[4];
  #pragma unroll
  for (int g = 0; g < 4; ++g) {
    const size_t r = (size_t)g * H + h;
    const float* wi = wih + r * IN;
    const float* wh = whh + r * (size_t)H;
    float a = 0.0f;
    for (int k = lane; k < IN; k += 64) a += wi[k] * xin[k];
    for (int k = lane; k < H;  k += 64) a += wh[k] * hprev[k];
    acc[g] = a;
  }
  #pragma unroll
  for (int off = 32; off > 0; off >>= 1) {
    #pragma unroll
    for (int g = 0; g < 4; ++g) acc[g] += __shfl_down(acc[g], off);
  }
  if (lane == 0) {
    const float* bi = p.b_ih[layer];
    const float* bh = p.b_hh[layer];
    const float gi = acc[0] + bi[h]         + bh[h];
    const float gf = acc[1] + bi[H + h]     + bh[H + h];
    const float gg = acc[2] + bi[2 * H + h] + bh[2 * H + h];
    const float go = acc[3] + bi[3 * H + h] + bh[3 * H + h];
    const float ig = 1.0f / (1.0f + expf(-gi));
    const float fg = 1.0f / (1.0f + expf(-gf));
    const float og = 1.0f / (1.0f + expf(-go));
    const float gt = tanhf(gg);
    const float cn = fg * p.c[layer][h] + ig * gt;
    const float hn = og * tanhf(cn);
    p.c[layer][h] = cn;
    hout[h] = hn;
    if (layer == 3) p.out[(size_t)t * 256 + h] = hn;
  }
}

// ===================== host launch ==========================================
extern "C" void kernel_launch(void* const* d_in, const int* in_sizes, int n_in,
                              void* d_out, int out_size, void* d_ws, size_t ws_size,
                              hipStream_t stream)
{
  const float* x    = (const float*)d_in[0];
  const float* bn_w = (const float*)d_in[1];
  const float* bn_b = (const float*)d_in[2];
  const float* wih[4]; const float* whh[4]; const float* bih[4]; const float* bhh[4];
  for (int l = 0; l < 4; ++l) {
    wih[l] = (const float*)d_in[3 + 4 * l];
    whh[l] = (const float*)d_in[4 + 4 * l];
    bih[l] = (const float*)d_in[5 + 4 * l];
    bhh[l] = (const float*)d_in[6 + 4 * l];
  }
  float* out = (float*)d_out;

  const size_t XN  = (size_t)NSTEP * 64;
  const size_t NH1 = (size_t)(NSTEP + 1) * 2048;
  const size_t NH2 = (size_t)(NSTEP + 1) * 1024;
  const size_t NH3 = (size_t)(NSTEP + 1) * 512;
  const size_t NH4 = (size_t)(NSTEP + 1) * 256;
  const size_t need = 4096 + (XN + NH1 + NH2 + NH3 + NH4) * sizeof(float);

  if (ws_size >= need) {
    unsigned* bar = (unsigned*)d_ws;               // 1024 u32: [0..255]=L1, [256..511]=fused
    float* fb = (float*)((char*)d_ws + 4096);
    float* xn = fb;
    float* H1 = xn + XN;
    float* H2 = H1 + NH1;
    float* H3 = H2 + NH2;
    float* H4 = H3 + NH3;

    hipMemsetAsync(bar, 0, 4096, stream);
    hipMemsetAsync(H1, 0, 2048 * sizeof(float), stream);
    hipMemsetAsync(H2, 0, 1024 * sizeof(float), stream);
    hipMemsetAsync(H3, 0,  512 * sizeof(float), stream);
    hipMemsetAsync(H4, 0,  256 * sizeof(float), stream);

    bn_kernel<<<1024, 256, 0, stream>>>(x, bn_w, bn_b, xn);

    lstm_l1<<<256, 512, 0, stream>>>(wih[0], whh[0], bih[0], bhh[0],
                                     xn, H1, bar);

    lstm_l234<<<224, 512, 0, stream>>>(wih[1], whh[1], bih[1], bhh[1],
                                       wih[2], whh[2], bih[2], bhh[2],
                                       wih[3], whh[3], bih[3], bhh[3],
                                       H1 + 2048, H2, H3, H4, out, bar + 256);
    return;
  }

  // -------- fallback: streaming pipeline (proven) --------
  Params p;
  for (int l = 0; l < 4; ++l) { p.w_ih[l] = wih[l]; p.w_hh[l] = whh[l];
                                p.b_ih[l] = bih[l]; p.b_hh[l] = bhh[l]; }
  float* ws = (float*)d_ws;
  float* xn = ws;
  float* st = ws + (size_t)NSTEP * 64;
  p.xn = xn;
  const int Hs[4] = {2048, 1024, 512, 256};
  float* cur = st;
  for (int l = 0; l < 4; ++l) { p.h[l] = cur; cur += 2 * Hs[l]; }
  for (int l = 0; l < 4; ++l) { p.c[l] = cur; cur += Hs[l]; }
  p.out = out;

  const size_t state_bytes = (size_t)(cur - st) * sizeof(float);
  hipMemsetAsync(st, 0, state_bytes, stream);
  bn_kernel<<<1024, 256, 0, stream>>>(x, bn_w, bn_b, xn);
  for (int s = 0; s < NSTEP + 3; ++s) {
    p.s = s;
    step_kernel<<<960, 256, 0, stream>>>(p);
  }
}

// Round 8
// 83132.666 us; speedup vs baseline: 3.1215x; 1.1009x over previous
//
#include <hip/hip_runtime.h>
#include <cstddef>

#define NSTEP 4096
// PIN a freshly-loaded temporary (plain local -> mem2reg-clean). Defining the
// value through volatile asm makes it unrematerializable; storing it into the
// persistent array afterwards keeps the array asm-free so SROA promotes it.
#define PIN1(x)  asm volatile("" : "+v"(x))
#define PIN4(v)  asm volatile("" : "+v"((v).x), "+v"((v).y), "+v"((v).z), "+v"((v).w))

// ===================== BatchNorm over timestep channels =====================
__global__ __launch_bounds__(256) void bn_kernel(const float* __restrict__ x,
                                                 const float* __restrict__ bn_w,
                                                 const float* __restrict__ bn_b,
                                                 float* __restrict__ xn)
{
  const int t   = blockIdx.x;        // 0..1023
  const int tid = threadIdx.x;       // 256 = B*F
  const int b   = tid >> 6;
  const int f   = tid & 63;
  const float v = x[((size_t)b * 1024 + t) * 64 + f];
  float s = v, ss = v * v;
  #pragma unroll
  for (int off = 32; off > 0; off >>= 1) {
    s  += __shfl_down(s, off);
    ss += __shfl_down(ss, off);
  }
  __shared__ float sh[8];
  const int w = tid >> 6;
  if ((tid & 63) == 0) { sh[w] = s; sh[4 + w] = ss; }
  __syncthreads();
  const float S    = sh[0] + sh[1] + sh[2] + sh[3];
  const float SS   = sh[4] + sh[5] + sh[6] + sh[7];
  const float mean = S * (1.0f / 256.0f);
  const float var  = SS * (1.0f / 256.0f) - mean * mean;  // biased, matches jnp.var
  const float inv  = rsqrtf(var + 1e-5f);
  const float scale = bn_w[t] * inv;
  const float shift = bn_b[t] - mean * scale;
  xn[((size_t)b * 1024 + t) * 64 + f] = v * scale + shift;
}

// ===================== grid barrier (proven in rounds 4-7) ==================
template<int NBLK>
__device__ __forceinline__ void grid_barrier(unsigned* __restrict__ bar,
                                             unsigned step1, int tid)
{
  constexpr unsigned GSZ = NBLK / 8;
  __syncthreads();
  if (tid == 0) {
    unsigned* gcnt = bar + 16 + 16 * (blockIdx.x / GSZ);
    unsigned* root = bar;
    __builtin_amdgcn_fence(__ATOMIC_RELEASE, "agent");
    const unsigned a = __hip_atomic_fetch_add(gcnt, 1u, __ATOMIC_RELAXED,
                                              __HIP_MEMORY_SCOPE_AGENT);
    if (a == step1 * GSZ - 1u)
      __hip_atomic_fetch_add(root, 1u, __ATOMIC_RELAXED, __HIP_MEMORY_SCOPE_AGENT);
    const unsigned tgt = step1 * 8u;
    while (__hip_atomic_load(root, __ATOMIC_RELAXED, __HIP_MEMORY_SCOPE_AGENT) < tgt)
      __builtin_amdgcn_s_sleep(2);
    __builtin_amdgcn_fence(__ATOMIC_ACQUIRE, "agent");
  }
  __syncthreads();
}

// ===================== wave helpers =========================================
__device__ __forceinline__ void reduce4(float& a0, float& a1, float& a2, float& a3)
{
  #pragma unroll
  for (int off = 32; off; off >>= 1) {
    a0 += __shfl_xor(a0, off);
    a1 += __shfl_xor(a1, off);
    a2 += __shfl_xor(a2, off);
    a3 += __shfl_xor(a3, off);
  }
}

__device__ __forceinline__ float lstm_act(float a0, float a1, float a2, float a3,
                                          const float* bsum, float& c)
{
  const float gi = a0 + bsum[0], gf = a1 + bsum[1];
  const float gg = a2 + bsum[2], go = a3 + bsum[3];
  const float ig = 1.0f / (1.0f + expf(-gi));
  const float fg = 1.0f / (1.0f + expf(-gf));
  const float og = 1.0f / (1.0f + expf(-go));
  c = fg * c + ig * tanhf(gg);
  return og * tanhf(c);
}

// ===================== Layer 1: W_ih (4) + W_hh (128) register-resident =====
__global__ __launch_bounds__(512, 1)
void lstm_l1(const float* __restrict__ win, const float* __restrict__ whh,
             const float* __restrict__ bih, const float* __restrict__ bhh,
             const float* __restrict__ X,     // (4096,64) normalized input
             float* __restrict__ Hout,        // (4097,2048), row r = h(r-1)
             unsigned* __restrict__ bar)
{
  constexpr int H = 2048, J4 = H / 256;       // 8 float4 per gate
  const int tid = threadIdx.x, lane = tid & 63, wsl = tid >> 6;
  const int hid = blockIdx.x * 8 + wsl;       // 2048 waves == H

  float  wi[4];
  float4 w[4][J4];
  float  bsum[4];
  #pragma unroll
  for (int g = 0; g < 4; ++g) {
    const size_t r = (size_t)g * H + hid;     // PyTorch gate order i,f,g,o
    { float t0 = win[r * 64 + lane]; PIN1(t0); wi[g] = t0; }
    const float4* wrow = (const float4*)(whh + r * (size_t)H);
    #pragma unroll
    for (int j = 0; j < J4; ++j) {
      float4 t = wrow[j * 64 + lane];
      PIN4(t);
      w[g][j] = t;
    }
    { float tb = bih[r] + bhh[r]; PIN1(tb); bsum[g] = tb; }
  }
  float c = 0.0f;

  #pragma unroll 1
  for (int t = 0; t < NSTEP; ++t) {
    const float xv = X[(size_t)t * 64 + lane];
    const float4* hrow = (const float4*)(Hout + (size_t)t * H);   // h(t-1)
    float a0 = wi[0] * xv, a1 = wi[1] * xv, a2 = wi[2] * xv, a3 = wi[3] * xv;
    #pragma unroll
    for (int j = 0; j < J4; ++j) {
      const float4 hv = hrow[j * 64 + lane];
      a0 = fmaf(w[0][j].x, hv.x, a0); a0 = fmaf(w[0][j].y, hv.y, a0);
      a0 = fmaf(w[0][j].z, hv.z, a0); a0 = fmaf(w[0][j].w, hv.w, a0);
      a1 = fmaf(w[1][j].x, hv.x, a1); a1 = fmaf(w[1][j].y, hv.y, a1);
      a1 = fmaf(w[1][j].z, hv.z, a1); a1 = fmaf(w[1][j].w, hv.w, a1);
      a2 = fmaf(w[2][j].x, hv.x, a2); a2 = fmaf(w[2][j].y, hv.y, a2);
      a2 = fmaf(w[2][j].z, hv.z, a2); a2 = fmaf(w[2][j].w, hv.w, a2);
      a3 = fmaf(w[3][j].x, hv.x, a3); a3 = fmaf(w[3][j].y, hv.y, a3);
      a3 = fmaf(w[3][j].z, hv.z, a3); a3 = fmaf(w[3][j].w, hv.w, a3);
    }
    reduce4(a0, a1, a2, a3);
    const float hn = lstm_act(a0, a1, a2, a3, bsum, c);
    if (lane == 0) Hout[(size_t)(t + 1) * H + hid] = hn;
    grid_barrier<256>(bar, (unsigned)(t + 1), tid);
  }
}

// ===================== fused L2+L3+L4 (pipelined, one barrier/step) =========
template<int IN, int H, int JT, bool LAST>
__device__ __forceinline__ void lstm_step(const float4* __restrict__ w,
                                          const float* __restrict__ bsum,
                                          float& c, int lane, int hid, int t,
                                          const float* __restrict__ X,     // row t = input(t), stride IN
                                          float* __restrict__ Hout,        // row r = h(r-1), stride H
                                          float* __restrict__ out)
{
  constexpr int JI = IN / 256, JH = H / 256;
  static_assert(JI + JH == JT, "JT mismatch");
  const float4* xrow = (const float4*)(X    + (size_t)t * IN);
  const float4* hrow = (const float4*)(Hout + (size_t)t * H);
  float a0 = 0.f, a1 = 0.f, a2 = 0.f, a3 = 0.f;
  #pragma unroll
  for (int j = 0; j < JI; ++j) {
    const float4 v = xrow[j * 64 + lane];
    a0 = fmaf(w[0*JT+j].x, v.x, a0); a0 = fmaf(w[0*JT+j].y, v.y, a0);
    a0 = fmaf(w[0*JT+j].z, v.z, a0); a0 = fmaf(w[0*JT+j].w, v.w, a0);
    a1 = fmaf(w[1*JT+j].x, v.x, a1); a1 = fmaf(w[1*JT+j].y, v.y, a1);
    a1 = fmaf(w[1*JT+j].z, v.z, a1); a1 = fmaf(w[1*JT+j].w, v.w, a1);
    a2 = fmaf(w[2*JT+j].x, v.x, a2); a2 = fmaf(w[2*JT+j].y, v.y, a2);
    a2 = fmaf(w[2*JT+j].z, v.z, a2); a2 = fmaf(w[2*JT+j].w, v.w, a2);
    a3 = fmaf(w[3*JT+j].x, v.x, a3); a3 = fmaf(w[3*JT+j].y, v.y, a3);
    a3 = fmaf(w[3*JT+j].z, v.z, a3); a3 = fmaf(w[3*JT+j].w, v.w, a3);
  }
  #pragma unroll
  for (int j = 0; j < JH; ++j) {
    const float4 v = hrow[j * 64 + lane];
    a0 = fmaf(w[0*JT+JI+j].x, v.x, a0); a0 = fmaf(w[0*JT+JI+j].y, v.y, a0);
    a0 = fmaf(w[0*JT+JI+j].z, v.z, a0); a0 = fmaf(w[0*JT+JI+j].w, v.w, a0);
    a1 = fmaf(w[1*JT+JI+j].x, v.x, a1); a1 = fmaf(w[1*JT+JI+j].y, v.y, a1);
    a1 = fmaf(w[1*JT+JI+j].z, v.z, a1); a1 = fmaf(w[1*JT+JI+j].w, v.w, a1);
    a2 = fmaf(w[2*JT+JI+j].x, v.x, a2); a2 = fmaf(w[2*JT+JI+j].y, v.y, a2);
    a2 = fmaf(w[2*JT+JI+j].z, v.z, a2); a2 = fmaf(w[2*JT+JI+j].w, v.w, a2);
    a3 = fmaf(w[3*JT+JI+j].x, v.x, a3); a3 = fmaf(w[3*JT+JI+j].y, v.y, a3);
    a3 = fmaf(w[3*JT+JI+j].w, v.w, a3); a3 = fmaf(w[3*JT+JI+j].z, v.z, a3);
  }
  reduce4(a0, a1, a2, a3);
  const float hn = lstm_act(a0, a1, a2, a3, bsum, c);
  if (lane == 0) {
    Hout[(size_t)(t + 1) * H + hid] = hn;
    if (LAST) out[(size_t)t * 256 + hid] = hn;
  }
}

__global__ __launch_bounds__(512, 1)
void lstm_l234(const float* __restrict__ win2, const float* __restrict__ whh2,
               const float* __restrict__ bih2, const float* __restrict__ bhh2,
               const float* __restrict__ win3, const float* __restrict__ whh3,
               const float* __restrict__ bih3, const float* __restrict__ bhh3,
               const float* __restrict__ win4, const float* __restrict__ whh4,
               const float* __restrict__ bih4, const float* __restrict__ bhh4,
               const float* __restrict__ X2,   // = H1 + 2048 (row t = h1(t))
               float* __restrict__ H2t, float* __restrict__ H3t,
               float* __restrict__ H4t, float* __restrict__ out,
               unsigned* __restrict__ bar)
{
  const int tid = threadIdx.x, lane = tid & 63, wsl = tid >> 6;
  const int gw = blockIdx.x * 8 + wsl;        // 0..1791

  // unioned weight storage: L2 uses 48 float4, L3 24, L4 12
  float4 w[48];
  float  bsum[4];
  #pragma unroll
  for (int i = 0; i < 48; ++i) w[i] = make_float4(0.f, 0.f, 0.f, 0.f);

  int hid;
  if (gw < 1024) {                            // L2: IN=2048 H=1024, JT=12
    hid = gw;
    #pragma unroll
    for (int g = 0; g < 4; ++g) {
      const size_t r = (size_t)g * 1024 + hid;
      const float4* wi = (const float4*)(win2 + r * 2048);
      const float4* wh = (const float4*)(whh2 + r * 1024);
      #pragma unroll
      for (int j = 0; j < 8; ++j) { float4 t = wi[j * 64 + lane]; PIN4(t); w[g * 12 + j] = t; }
      #pragma unroll
      for (int j = 0; j < 4; ++j) { float4 t = wh[j * 64 + lane]; PIN4(t); w[g * 12 + 8 + j] = t; }
      { float tb = bih2[r] + bhh2[r]; PIN1(tb); bsum[g] = tb; }
    }
  } else if (gw < 1536) {                     // L3: IN=1024 H=512, JT=6
    hid = gw - 1024;
    #pragma unroll
    for (int g = 0; g < 4; ++g) {
      const size_t r = (size_t)g * 512 + hid;
      const float4* wi = (const float4*)(win3 + r * 1024);
      const float4* wh = (const float4*)(whh3 + r * 512);
      #pragma unroll
      for (int j = 0; j < 4; ++j) { float4 t = wi[j * 64 + lane]; PIN4(t); w[g * 6 + j] = t; }
      #pragma unroll
      for (int j = 0; j < 2; ++j) { float4 t = wh[j * 64 + lane]; PIN4(t); w[g * 6 + 4 + j] = t; }
      { float tb = bih3[r] + bhh3[r]; PIN1(tb); bsum[g] = tb; }
    }
  } else {                                    // L4: IN=512 H=256, JT=3
    hid = gw - 1536;
    #pragma unroll
    for (int g = 0; g < 4; ++g) {
      const size_t r = (size_t)g * 256 + hid;
      const float4* wi = (const float4*)(win4 + r * 512);
      const float4* wh = (const float4*)(whh4 + r * 256);
      #pragma unroll
      for (int j = 0; j < 2; ++j) { float4 t = wi[j * 64 + lane]; PIN4(t); w[g * 3 + j] = t; }
      { float4 t = wh[lane]; PIN4(t); w[g * 3 + 2] = t; }
      { float tb = bih4[r] + bhh4[r]; PIN1(tb); bsum[g] = tb; }
    }
  }

  float c = 0.0f;

  #pragma unroll 1
  for (int s = 0; s < NSTEP + 2; ++s) {
    if (gw < 1024) {
      if (s < NSTEP)
        lstm_step<2048, 1024, 12, false>(w, bsum, c, lane, hid, s, X2, H2t, nullptr);
    } else if (gw < 1536) {
      if (s >= 1 && s <= NSTEP)
        lstm_step<1024, 512, 6, false>(w, bsum, c, lane, hid, s - 1, H2t + 1024, H3t, nullptr);
    } else {
      if (s >= 2)
        lstm_step<512, 256, 3, true>(w, bsum, c, lane, hid, s - 2, H3t + 512, H4t, out);
    }
    grid_barrier<224>(bar, (unsigned)(s + 1), tid);
  }
}

// ===================== Fallback: round-1 streaming path =====================
struct Params {
  const float* xn;
  const float* w_ih[4];
  const float* w_hh[4];
  const float* b_ih[4];
  const float* b_hh[4];
  float* h[4];
  float* c[4];
  float* out;
  int s;
};

__global__ __launch_bounds__(256) void step_kernel(Params p)
{
  const int lane = threadIdx.x & 63;
  const int W = blockIdx.x * 4 + (threadIdx.x >> 6);

  int layer, h, H, IN, t;
  if (W < 2048)      { layer = 0; h = W;        H = 2048; IN = 64;   t = p.s;     }
  else if (W < 3072) { layer = 1; h = W - 2048; H = 1024; IN = 2048; t = p.s - 1; }
  else if (W < 3584) { layer = 2; h = W - 3072; H = 512;  IN = 1024; t = p.s - 2; }
  else               { layer = 3; h = W - 3584; H = 256;  IN = 512;  t = p.s - 3; }
  if (t < 0 || t >= NSTEP) return;

  const float* xin;
  if (layer == 0) xin = p.xn + (size_t)t * 64;
  else            xin = p.h[layer - 1] + (size_t)(t & 1) * IN;
  const float* hprev = p.h[layer] + (size_t)((t + 1) & 1) * H;
  float*       hout  = p.h[layer] + (size_t)(t & 1) * H;
  const float* wih = p.w_ih[layer];
  const float* whh = p.w_hh[layer];

  float acc[4];
  #pragma unroll
  for (int g = 0; g < 4; ++g) {
    const size_t r = (size_t)g * H + h;
    const float* wi = wih + r * IN;
    const float* wh = whh + r * (size_t)H;
    float a = 0.0f;
    for (int k = lane; k < IN; k += 64) a += wi[k] * xin[k];
    for (int k = lane; k < H;  k += 64) a += wh[k] * hprev[k];
    acc[g] = a;
  }
  #pragma unroll
  for (int off = 32; off > 0; off >>= 1) {
    #pragma unroll
    for (int g = 0; g < 4; ++g) acc[g] += __shfl_down(acc[g], off);
  }
  if (lane == 0) {
    const float* bi = p.b_ih[layer];
    const float* bh = p.b_hh[layer];
    const float gi = acc[0] + bi[h]         + bh[h];
    const float gf = acc[1] + bi[H + h]     + bh[H + h];
    const float gg = acc[2] + bi[2 * H + h] + bh[2 * H + h];
    const float go = acc[3] + bi[3 * H + h] + bh[3 * H + h];
    const float ig = 1.0f / (1.0f + expf(-gi));
    const float fg = 1.0f / (1.0f + expf(-gf));
    const float og = 1.0f / (1.0f + expf(-go));
    const float gt = tanhf(gg);
    const float cn = fg * p.c[layer][h] + ig * gt;
    const float hn = og * tanhf(cn);
    p.c[layer][h] = cn;
    hout[h] = hn;
    if (layer == 3) p.out[(size_t)t * 256 + h] = hn;
  }
}

// ===================== host launch ==========================================
extern "C" void kernel_launch(void* const* d_in, const int* in_sizes, int n_in,
                              void* d_out, int out_size, void* d_ws, size_t ws_size,
                              hipStream_t stream)
{
  const float* x    = (const float*)d_in[0];
  const float* bn_w = (const float*)d_in[1];
  const float* bn_b = (const float*)d_in[2];
  const float* wih[4]; const float* whh[4]; const float* bih[4]; const float* bhh[4];
  for (int l = 0; l < 4; ++l) {
    wih[l] = (const float*)d_in[3 + 4 * l];
    whh[l] = (const float*)d_in[4 + 4 * l];
    bih[l] = (const float*)d_in[5 + 4 * l];
    bhh[l] = (const float*)d_in[6 + 4 * l];
  }
  float* out = (float*)d_out;

  const size_t XN  = (size_t)NSTEP * 64;
  const size_t NH1 = (size_t)(NSTEP + 1) * 2048;
  const size_t NH2 = (size_t)(NSTEP + 1) * 1024;
  const size_t NH3 = (size_t)(NSTEP + 1) * 512;
  const size_t NH4 = (size_t)(NSTEP + 1) * 256;
  const size_t need = 4096 + (XN + NH1 + NH2 + NH3 + NH4) * sizeof(float);

  if (ws_size >= need) {
    unsigned* bar = (unsigned*)d_ws;               // 1024 u32: [0..255]=L1, [256..511]=fused
    float* fb = (float*)((char*)d_ws + 4096);
    float* xn = fb;
    float* H1 = xn + XN;
    float* H2 = H1 + NH1;
    float* H3 = H2 + NH2;
    float* H4 = H3 + NH3;

    hipMemsetAsync(bar, 0, 4096, stream);
    hipMemsetAsync(H1, 0, 2048 * sizeof(float), stream);
    hipMemsetAsync(H2, 0, 1024 * sizeof(float), stream);
    hipMemsetAsync(H3, 0,  512 * sizeof(float), stream);
    hipMemsetAsync(H4, 0,  256 * sizeof(float), stream);

    bn_kernel<<<1024, 256, 0, stream>>>(x, bn_w, bn_b, xn);

    lstm_l1<<<256, 512, 0, stream>>>(wih[0], whh[0], bih[0], bhh[0],
                                     xn, H1, bar);

    lstm_l234<<<224, 512, 0, stream>>>(wih[1], whh[1], bih[1], bhh[1],
                                       wih[2], whh[2], bih[2], bhh[2],
                                       wih[3], whh[3], bih[3], bhh[3],
                                       H1 + 2048, H2, H3, H4, out, bar + 256);
    return;
  }

  // -------- fallback: streaming pipeline (proven) --------
  Params p;
  for (int l = 0; l < 4; ++l) { p.w_ih[l] = wih[l]; p.w_hh[l] = whh[l];
                                p.b_ih[l] = bih[l]; p.b_hh[l] = bhh[l]; }
  float* ws = (float*)d_ws;
  float* xn = ws;
  float* st = ws + (size_t)NSTEP * 64;
  p.xn = xn;
  const int Hs[4] = {2048, 1024, 512, 256};
  float* cur = st;
  for (int l = 0; l < 4; ++l) { p.h[l] = cur; cur += 2 * Hs[l]; }
  for (int l = 0; l < 4; ++l) { p.c[l] = cur; cur += Hs[l]; }
  p.out = out;

  const size_t state_bytes = (size_t)(cur - st) * sizeof(float);
  hipMemsetAsync(st, 0, state_bytes, stream);
  bn_kernel<<<1024, 256, 0, stream>>>(x, bn_w, bn_b, xn);
  for (int s = 0; s < NSTEP + 3; ++s) {
    p.s = s;
    step_kernel<<<960, 256, 0, stream>>>(p);
  }
}